// Round 4
// baseline (264.583 us; speedup 1.0000x reference)
//
#include <hip/hip_runtime.h>
#include <stdint.h>

// ----------------------------------------------------------------------------
// SparseKVCache: keep top-k by |x| (k = n/2), zero the rest. Exact.
// R4: sampled bracket -> ONE fused full pass, unrolled x4 (independent loads
// for MLP), branchless definite-output write + exact above-count + rare
// in-bracket gather (small LDS stage, global overflow) -> exact select on
// candidate set -> scatter-fixup. Stable ties = smallest indices.
// ----------------------------------------------------------------------------

#define NTHR 256
#define MASK31 0x7fffffffu

// ---- ws layout (uint32 words) ----
#define SH_OFF    0           // 8192-bin sample histogram (bits 30..18)
#define SH_BINS   8192
#define CH_OFF    8192        // 4096-bin candidate histogram
#define CH_BINS   4096
#define SCL_OFF   12288       // scalars:
//  [0]=bLo [1]=bHi [2]=shift1 [3]=spanBase [4]=cntHi [5]=gCount
//  [6]=base2 [7]=rem2 [8]=c3
#define L3_OFF    12320       // level-3 pairs (uint2), even word => 8B aligned
#define L3_CAP    4096
#define PAIRS_OFF (L3_OFF + 2 * L3_CAP)   // even => 8B aligned
#define PAIRS_CAP 4194304                  // 4M pairs = 32 MB
#define ZERO_WORDS (SCL_OFF + 32)

#define GC_CAP    512         // per-block LDS pair stage (4 KB)
#define TIE_CAP   1024

__global__ void zero_ws_kernel(uint32_t* __restrict__ ws) {
    int i = blockIdx.x * blockDim.x + threadIdx.x;
    if (i < ZERO_WORDS) ws[i] = 0;
}

// ---- sample histogram: 1M scalar samples, phase-mixed (decorrelates with
// the 512B inner-dim structure of the KV layout) ------------------------------
__global__ void sample_hist_kernel(const uint4* __restrict__ xv, long long n4,
                                   uint32_t* __restrict__ ws) {
    __shared__ uint32_t lh[SH_BINS];
    for (int i = threadIdx.x; i < SH_BINS; i += NTHR) lh[i] = 0;
    __syncthreads();
    long long S4 = n4 >> 5;
    long long T = (long long)gridDim.x * NTHR;
    for (long long s = (long long)blockIdx.x * NTHR + threadIdx.x; s < S4; s += T) {
        long long idx4 = (s << 5) | (s & 31);   // strictly increasing, distinct
        uint4 v = xv[idx4];
        atomicAdd(&lh[(v.x & MASK31) >> 18], 1u);
        atomicAdd(&lh[(v.y & MASK31) >> 18], 1u);
        atomicAdd(&lh[(v.z & MASK31) >> 18], 1u);
        atomicAdd(&lh[(v.w & MASK31) >> 18], 1u);
    }
    __syncthreads();
    for (int i = threadIdx.x; i < SH_BINS; i += NTHR)
        if (lh[i]) atomicAdd(&ws[SH_OFF + i], lh[i]);
}

// ---- bracket select from sample histogram -----------------------------------
__global__ void sel_bracket_kernel(uint32_t* __restrict__ ws,
                                   uint32_t ksmM, uint32_t kspM) {
    __shared__ uint32_t lh[SH_BINS];
    __shared__ uint32_t csum[NTHR];
    __shared__ uint32_t cpre[NTHR];
    __shared__ int sBHi, sB1;
    for (int i = threadIdx.x; i < SH_BINS; i += NTHR) lh[i] = ws[SH_OFF + i];
    if (threadIdx.x == 0) { sBHi = -1; sB1 = -1; }
    __syncthreads();
    uint32_t s = 0;
    for (int i = 0; i < 32; ++i) s += lh[threadIdx.x * 32 + i];
    csum[threadIdx.x] = s;
    __syncthreads();
    if (threadIdx.x == 0) {
        uint32_t run = 0;
        for (int c = NTHR - 1; c >= 0; --c) { cpre[c] = run; run += csum[c]; }
    }
    __syncthreads();
    {
        int c = threadIdx.x;
        int hitHi = -1, hitB1 = -1;
        uint32_t excl = cpre[c];
        for (int bb = c * 32 + 31; bb >= c * 32; --bb) {
            uint32_t cnt = lh[bb];
            uint32_t incl = excl + cnt;
            if (hitHi < 0 && incl >= ksmM) hitHi = bb;
            if (hitB1 < 0 && excl >= kspM) hitB1 = bb;
            excl = incl;
        }
        if (hitHi >= 0) atomicMax(&sBHi, hitHi);
        if (hitB1 >= 0) atomicMax(&sB1, hitB1);
    }
    __syncthreads();
    if (threadIdx.x == 0) {
        int bHi = sBHi < 0 ? 0 : sBHi;
        int bLo = sB1 + 1;
        if (bLo > bHi) bLo = bHi;
        if (bLo < 0) bLo = 0;
        int span = bHi - bLo + 1;
        int clog = 0; while ((1 << clog) < span) ++clog;
        int spanBits = 18 + clog;
        int shift1 = spanBits > 12 ? spanBits - 12 : 0;
        ws[SCL_OFF + 0] = (uint32_t)bLo;
        ws[SCL_OFF + 1] = (uint32_t)bHi;
        ws[SCL_OFF + 2] = (uint32_t)shift1;
        ws[SCL_OFF + 3] = ((uint32_t)bLo) << 18;
    }
}

// ---- fused full pass: unrolled x4, branchless writes, rare gather ----------
__global__ __launch_bounds__(NTHR, 6)
void fused_main_kernel(const uint32_t* __restrict__ x, uint32_t* __restrict__ out,
                       long long n, uint32_t* __restrict__ ws) {
    __shared__ uint2 stage[GC_CAP];
    __shared__ uint32_t cnt, sHi, sBase;
    const uint32_t bLo = ws[SCL_OFF + 0], bHi = ws[SCL_OFF + 1];
    const uint32_t bSpan = bHi - bLo;
    if (threadIdx.x == 0) { cnt = 0u; sHi = 0u; }
    __syncthreads();
    uint32_t myHi = 0;
    uint2* __restrict__ gpairs = (uint2*)(ws + PAIRS_OFF);

    const uint4* __restrict__ xv = (const uint4*)x;
    uint4* __restrict__ ov = (uint4*)out;
    long long n4 = n >> 2;
    long long nChunks = n4 / (NTHR * 4);   // 1024 uint4 per chunk

#define PUSH_PAIR(val, eidx) { \
    uint32_t p_ = atomicAdd(&cnt, 1u); \
    uint2 pr_ = make_uint2((val), (eidx)); \
    if (p_ < GC_CAP) stage[p_] = pr_; \
    else { uint32_t g_ = atomicAdd(&ws[SCL_OFF + 5], 1u); if (g_ < PAIRS_CAP) gpairs[g_] = pr_; } }

#define COMP(val, eidx) { \
    uint32_t u_ = (val) & MASK31; uint32_t b_ = u_ >> 18; \
    uint32_t hi_ = (b_ > bHi) ? 1u : 0u; myHi += hi_; \
    if (b_ - bLo <= bSpan) PUSH_PAIR((val), (eidx)); \
    (val) = hi_ ? (val) : 0u; }

    if ((long long)blockIdx.x < nChunks) {
        long long i0 = (long long)blockIdx.x * (NTHR * 4) + threadIdx.x;
        uint4 v0 = xv[i0];
        uint4 v1 = xv[i0 + NTHR];
        uint4 v2 = xv[i0 + 2 * NTHR];
        uint4 v3 = xv[i0 + 3 * NTHR];
        uint32_t e0 = (uint32_t)(i0 << 2);
        uint32_t e1 = e0 + NTHR * 4;
        uint32_t e2 = e0 + 2 * NTHR * 4;
        uint32_t e3 = e0 + 3 * NTHR * 4;
        COMP(v0.x, e0 + 0) COMP(v0.y, e0 + 1) COMP(v0.z, e0 + 2) COMP(v0.w, e0 + 3)
        COMP(v1.x, e1 + 0) COMP(v1.y, e1 + 1) COMP(v1.z, e1 + 2) COMP(v1.w, e1 + 3)
        COMP(v2.x, e2 + 0) COMP(v2.y, e2 + 1) COMP(v2.z, e2 + 2) COMP(v2.w, e2 + 3)
        COMP(v3.x, e3 + 0) COMP(v3.y, e3 + 1) COMP(v3.z, e3 + 2) COMP(v3.w, e3 + 3)
        ov[i0]            = v0;
        ov[i0 + NTHR]     = v1;
        ov[i0 + 2 * NTHR] = v2;
        ov[i0 + 3 * NTHR] = v3;
    }

    // tail (elements beyond full chunks) handled by block 0; empty for n = 2^25
    long long tailStart = nChunks * (NTHR * 4) * 4;
    if (blockIdx.x == 0) {
        for (long long idx = tailStart + threadIdx.x; idx < n; idx += NTHR) {
            uint32_t v = x[idx];
            uint32_t u_ = v & MASK31, b_ = u_ >> 18;
            uint32_t hi_ = (b_ > bHi) ? 1u : 0u; myHi += hi_;
            if (b_ - bLo <= bSpan) PUSH_PAIR(v, (uint32_t)idx);
            out[idx] = hi_ ? v : 0u;
        }
    }

    if (myHi) atomicAdd(&sHi, myHi);
    __syncthreads();
    if (threadIdx.x == 0) {
        uint32_t c = cnt < GC_CAP ? cnt : GC_CAP;
        cnt = c;
        sBase = atomicAdd(&ws[SCL_OFF + 5], c);
        if (sHi) atomicAdd(&ws[SCL_OFF + 4], sHi);
    }
    __syncthreads();
    uint32_t c = cnt, b0 = sBase;
    for (uint32_t q = threadIdx.x; q < c; q += NTHR)
        if (b0 + q < PAIRS_CAP) gpairs[b0 + q] = stage[q];
#undef COMP
#undef PUSH_PAIR
}

// ---- candidate histogram ----------------------------------------------------
__global__ void cand_hist_kernel(uint32_t* __restrict__ ws) {
    __shared__ uint32_t lh[CH_BINS];
    uint32_t G = ws[SCL_OFF + 5]; if (G > PAIRS_CAP) G = PAIRS_CAP;
    uint32_t spanBase = ws[SCL_OFF + 3], shift1 = ws[SCL_OFF + 2];
    for (int i = threadIdx.x; i < CH_BINS; i += NTHR) lh[i] = 0;
    __syncthreads();
    const uint2* pairs = (const uint2*)(ws + PAIRS_OFF);
    uint32_t stride = gridDim.x * NTHR;
    for (uint32_t i = blockIdx.x * NTHR + threadIdx.x; i < G; i += stride) {
        uint32_t u = pairs[i].x & MASK31;
        atomicAdd(&lh[((u - spanBase) >> shift1) & (CH_BINS - 1)], 1u);
    }
    __syncthreads();
    for (int i = threadIdx.x; i < CH_BINS; i += NTHR)
        if (lh[i]) atomicAdd(&ws[CH_OFF + i], lh[i]);
}

// ---- level-2 select (redundant per block) + gather in-bin pairs -------------
__global__ void sel_gather_kernel(uint32_t* __restrict__ ws, uint32_t k) {
    __shared__ uint32_t lh[CH_BINS];
    __shared__ uint32_t csum[NTHR];
    __shared__ uint32_t cpre[NTHR];
    __shared__ uint32_t sBase2, sRem2;
    for (int i = threadIdx.x; i < CH_BINS; i += NTHR) lh[i] = ws[CH_OFF + i];
    __syncthreads();
    uint32_t kp = k - ws[SCL_OFF + 4];
    uint32_t s = 0;
    for (int i = 0; i < 16; ++i) s += lh[threadIdx.x * 16 + i];
    csum[threadIdx.x] = s;
    __syncthreads();
    if (threadIdx.x == 0) {
        uint32_t run = 0;
        for (int c = NTHR - 1; c >= 0; --c) { cpre[c] = run; run += csum[c]; }
    }
    __syncthreads();
    if (cpre[threadIdx.x] < kp && kp <= cpre[threadIdx.x] + csum[threadIdx.x]) {
        uint32_t excl = cpre[threadIdx.x];
        for (int bb = threadIdx.x * 16 + 15; bb >= threadIdx.x * 16; --bb) {
            uint32_t cnt = lh[bb];
            if (excl + cnt >= kp) {
                sBase2 = ws[SCL_OFF + 3] + (((uint32_t)bb) << ws[SCL_OFF + 2]);
                sRem2 = kp - excl;
                break;
            }
            excl += cnt;
        }
    }
    __syncthreads();
    if (threadIdx.x == 0) { ws[SCL_OFF + 6] = sBase2; ws[SCL_OFF + 7] = sRem2; }
    uint32_t base2 = sBase2;
    uint32_t width = 1u << ws[SCL_OFF + 2];
    uint32_t G = ws[SCL_OFF + 5]; if (G > PAIRS_CAP) G = PAIRS_CAP;
    const uint2* pairs = (const uint2*)(ws + PAIRS_OFF);
    uint2* l3 = (uint2*)(ws + L3_OFF);
    uint32_t stride = gridDim.x * NTHR;
    for (uint32_t i = blockIdx.x * NTHR + threadIdx.x; i < G; i += stride) {
        uint2 pr = pairs[i];
        uint32_t u = pr.x & MASK31;
        if (u - base2 < width) {
            uint32_t p = atomicAdd(&ws[SCL_OFF + 8], 1u);
            if (p < L3_CAP) l3[p] = pr;
        }
    }
}

// ---- final select (redundant per block) + scatter-fixup kept candidates ----
__global__ void final_fixup_kernel(uint32_t* __restrict__ ws,
                                   uint32_t* __restrict__ out) {
    __shared__ uint32_t lh[CH_BINS];
    __shared__ uint32_t csum[NTHR];
    __shared__ uint32_t cpre[NTHR];
    __shared__ uint32_t tieIdx[TIE_CAP];
    __shared__ uint32_t tieCnt, sT, sJ, sTieMax;
    uint32_t c3 = ws[SCL_OFF + 8]; if (c3 > L3_CAP) c3 = L3_CAP;
    uint32_t base2 = ws[SCL_OFF + 6], rem2 = ws[SCL_OFF + 7];
    for (int i = threadIdx.x; i < CH_BINS; i += NTHR) lh[i] = 0;
    if (threadIdx.x == 0) tieCnt = 0;
    __syncthreads();
    const uint2* l3 = (const uint2*)(ws + L3_OFF);
    for (uint32_t i = threadIdx.x; i < c3; i += NTHR) {
        uint32_t u = l3[i].x & MASK31;
        atomicAdd(&lh[(u - base2) & (CH_BINS - 1)], 1u);
    }
    __syncthreads();
    uint32_t s = 0;
    for (int i = 0; i < 16; ++i) s += lh[threadIdx.x * 16 + i];
    csum[threadIdx.x] = s;
    __syncthreads();
    if (threadIdx.x == 0) {
        uint32_t run = 0;
        for (int c = NTHR - 1; c >= 0; --c) { cpre[c] = run; run += csum[c]; }
    }
    __syncthreads();
    if (cpre[threadIdx.x] < rem2 && rem2 <= cpre[threadIdx.x] + csum[threadIdx.x]) {
        uint32_t excl = cpre[threadIdx.x];
        for (int bb = threadIdx.x * 16 + 15; bb >= threadIdx.x * 16; --bb) {
            uint32_t cnt = lh[bb];
            if (excl + cnt >= rem2) { sT = base2 + (uint32_t)bb; sJ = rem2 - excl; break; }
            excl += cnt;
        }
    }
    __syncthreads();
    uint32_t t = sT;
    for (uint32_t i = threadIdx.x; i < c3; i += NTHR) {
        uint2 pr = l3[i];
        if ((pr.x & MASK31) == t) {
            uint32_t p = atomicAdd(&tieCnt, 1u);
            if (p < TIE_CAP) tieIdx[p] = pr.y;
        }
    }
    __syncthreads();
    if (threadIdx.x == 0) {
        uint32_t m = tieCnt < TIE_CAP ? tieCnt : TIE_CAP;
        for (uint32_t a = 1; a < m; ++a) {   // tiny insertion sort
            uint32_t v = tieIdx[a]; int bp = (int)a - 1;
            while (bp >= 0 && tieIdx[bp] > v) { tieIdx[bp + 1] = tieIdx[bp]; --bp; }
            tieIdx[bp + 1] = v;
        }
        uint32_t j = sJ;
        if (j > m) j = m;
        sJ = j;
        sTieMax = (j > 0) ? tieIdx[j - 1] : 0u;
    }
    __syncthreads();
    uint32_t j = sJ, tieMax = sTieMax;
    uint32_t G = ws[SCL_OFF + 5]; if (G > PAIRS_CAP) G = PAIRS_CAP;
    const uint2* pairs = (const uint2*)(ws + PAIRS_OFF);
    uint32_t stride = gridDim.x * NTHR;
    for (uint32_t i = blockIdx.x * NTHR + threadIdx.x; i < G; i += stride) {
        uint2 pr = pairs[i];
        uint32_t u = pr.x & MASK31;
        bool keep = (u > t) || (u == t && j > 0 && pr.y <= tieMax);
        if (keep) out[pr.y] = pr.x;
    }
}

extern "C" void kernel_launch(void* const* d_in, const int* in_sizes, int n_in,
                              void* d_out, int out_size, void* d_ws, size_t ws_size,
                              hipStream_t stream) {
    const uint32_t* x = (const uint32_t*)d_in[0];
    uint32_t* out = (uint32_t*)d_out;
    uint32_t* ws = (uint32_t*)d_ws;
    long long n = (long long)in_sizes[0];

    const double ratio = 0.5;  // SPARSE_COMPRESSION_RATIO
    long long k = (long long)((double)n * (1.0 - ratio));
    if (k < 1) k = 1;
    if (k > n) k = n;

    long long n4 = n >> 2;
    long long S = (n4 >> 5) << 2;           // 4 samples per 32 uint4s
    long long ks = (long long)((double)k * ((double)S / (double)n));
    const long long M = 4500;               // ~8.8 sigma at S=1,048,576
    uint32_t ksmM = (uint32_t)((ks - M) < 1 ? 1 : (ks - M));
    uint32_t kspM = (uint32_t)((ks + M) > S ? S : (ks + M));

    long long nChunks = n4 / (NTHR * 4);
    int grid = (int)(nChunks < 1 ? 1 : nChunks);

    zero_ws_kernel<<<(ZERO_WORDS + NTHR - 1) / NTHR, NTHR, 0, stream>>>(ws);
    sample_hist_kernel<<<128, NTHR, 0, stream>>>((const uint4*)x, n4, ws);
    sel_bracket_kernel<<<1, NTHR, 0, stream>>>(ws, ksmM, kspM);
    fused_main_kernel<<<grid, NTHR, 0, stream>>>(x, out, n, ws);
    cand_hist_kernel<<<128, NTHR, 0, stream>>>(ws);
    sel_gather_kernel<<<128, NTHR, 0, stream>>>(ws, (uint32_t)k);
    final_fixup_kernel<<<128, NTHR, 0, stream>>>(ws, out);
}

// Round 5
// 145.835 us; speedup vs baseline: 1.8143x; 1.8143x over previous
//
#include <hip/hip_runtime.h>
#include <stdint.h>

// ----------------------------------------------------------------------------
// SparseKVCache: keep top-k by |x| (k = n/2), zero the rest. Exact.
// R5: sampled bracket -> ONE fused full pass with 8x independent uint4 loads
// (static register array, no atomics between load and compute -> compiler
// pipelines), branchless value-space classify into a per-lane hitmask, rare
// push path AFTER stores -> exact select on candidate set -> scatter-fixup.
// Stable ties = smallest indices. Deterministic.
// ----------------------------------------------------------------------------

#define NTHR 256
#define MASK31 0x7fffffffu

// ---- ws layout (uint32 words) ----
#define SH_OFF    0           // 8192-bin sample histogram (bits 30..18)
#define SH_BINS   8192
#define CH_OFF    8192        // 4096-bin candidate histogram
#define CH_BINS   4096
#define SCL_OFF   12288       // scalars:
//  [0]=bLo [1]=bHi [2]=shift1 [3]=spanBase [4]=cntHi [5]=gCount
//  [6]=base2 [7]=rem2 [8]=c3
#define L3_OFF    12320       // level-3 pairs (uint2), even word => 8B aligned
#define L3_CAP    4096
#define PAIRS_OFF (L3_OFF + 2 * L3_CAP)   // even => 8B aligned
#define PAIRS_CAP 4194304                  // 4M pairs = 32 MB
#define ZERO_WORDS (SCL_OFF + 32)

#define STG_CAP   2048        // per-block LDS pair stage (16 KB)
#define TIE_CAP   1024

__global__ void zero_ws_kernel(uint32_t* __restrict__ ws) {
    int i = blockIdx.x * blockDim.x + threadIdx.x;
    if (i < ZERO_WORDS) ws[i] = 0;
}

// ---- sample histogram: 1M scalar samples, phase-mixed ----------------------
__global__ void sample_hist_kernel(const uint4* __restrict__ xv, long long n4,
                                   uint32_t* __restrict__ ws) {
    __shared__ uint32_t lh[SH_BINS];
    for (int i = threadIdx.x; i < SH_BINS; i += NTHR) lh[i] = 0;
    __syncthreads();
    long long S4 = n4 >> 5;
    long long T = (long long)gridDim.x * NTHR;
    for (long long s = (long long)blockIdx.x * NTHR + threadIdx.x; s < S4; s += T) {
        long long idx4 = (s << 5) | (s & 31);   // strictly increasing, distinct
        uint4 v = xv[idx4];
        atomicAdd(&lh[(v.x & MASK31) >> 18], 1u);
        atomicAdd(&lh[(v.y & MASK31) >> 18], 1u);
        atomicAdd(&lh[(v.z & MASK31) >> 18], 1u);
        atomicAdd(&lh[(v.w & MASK31) >> 18], 1u);
    }
    __syncthreads();
    for (int i = threadIdx.x; i < SH_BINS; i += NTHR)
        if (lh[i]) atomicAdd(&ws[SH_OFF + i], lh[i]);
}

// ---- bracket select from sample histogram -----------------------------------
__global__ void sel_bracket_kernel(uint32_t* __restrict__ ws,
                                   uint32_t ksmM, uint32_t kspM) {
    __shared__ uint32_t lh[SH_BINS];
    __shared__ uint32_t csum[NTHR];
    __shared__ uint32_t cpre[NTHR];
    __shared__ int sBHi, sB1;
    for (int i = threadIdx.x; i < SH_BINS; i += NTHR) lh[i] = ws[SH_OFF + i];
    if (threadIdx.x == 0) { sBHi = -1; sB1 = -1; }
    __syncthreads();
    uint32_t s = 0;
    for (int i = 0; i < 32; ++i) s += lh[threadIdx.x * 32 + i];
    csum[threadIdx.x] = s;
    __syncthreads();
    if (threadIdx.x == 0) {
        uint32_t run = 0;
        for (int c = NTHR - 1; c >= 0; --c) { cpre[c] = run; run += csum[c]; }
    }
    __syncthreads();
    {
        int c = threadIdx.x;
        int hitHi = -1, hitB1 = -1;
        uint32_t excl = cpre[c];
        for (int bb = c * 32 + 31; bb >= c * 32; --bb) {
            uint32_t cnt = lh[bb];
            uint32_t incl = excl + cnt;
            if (hitHi < 0 && incl >= ksmM) hitHi = bb;
            if (hitB1 < 0 && excl >= kspM) hitB1 = bb;
            excl = incl;
        }
        if (hitHi >= 0) atomicMax(&sBHi, hitHi);
        if (hitB1 >= 0) atomicMax(&sB1, hitB1);
    }
    __syncthreads();
    if (threadIdx.x == 0) {
        int bHi = sBHi < 0 ? 0 : sBHi;
        int bLo = sB1 + 1;
        if (bLo > bHi) bLo = bHi;
        if (bLo < 0) bLo = 0;
        int span = bHi - bLo + 1;
        int clog = 0; while ((1 << clog) < span) ++clog;
        int spanBits = 18 + clog;
        int shift1 = spanBits > 12 ? spanBits - 12 : 0;
        ws[SCL_OFF + 0] = (uint32_t)bLo;
        ws[SCL_OFF + 1] = (uint32_t)bHi;
        ws[SCL_OFF + 2] = (uint32_t)shift1;
        ws[SCL_OFF + 3] = ((uint32_t)bLo) << 18;
    }
}

// ---- fused full pass --------------------------------------------------------
__global__ void fused_main_kernel(const uint32_t* __restrict__ x,
                                  uint32_t* __restrict__ out, long long n,
                                  uint32_t* __restrict__ ws) {
    __shared__ uint2 stage[STG_CAP];
    __shared__ uint32_t cnt, sHi, sBase;
    const uint32_t uLo = ws[SCL_OFF + 0] << 18;
    const uint32_t uHi = (ws[SCL_OFF + 1] + 1u) << 18;   // exclusive top bound
    const uint32_t span = uHi - uLo;
    if (threadIdx.x == 0) { cnt = 0u; sHi = 0u; }
    __syncthreads();
    uint32_t myHi = 0;
    uint2* __restrict__ gpairs = (uint2*)(ws + PAIRS_OFF);

    const uint4* __restrict__ xv = (const uint4*)x;
    uint4* __restrict__ ov = (uint4*)out;
    long long n4 = n >> 2;
    long long nChunk = n4 >> 11;           // 2048 uint4 per chunk

#define PUSH_PAIR(val, eidx) { \
    uint32_t p_ = atomicAdd(&cnt, 1u); \
    uint2 pr_ = make_uint2((val), (eidx)); \
    if (p_ < STG_CAP) stage[p_] = pr_; \
    else { uint32_t g_ = atomicAdd(&ws[SCL_OFF + 5], 1u); if (g_ < PAIRS_CAP) gpairs[g_] = pr_; } }

    for (long long c = blockIdx.x; c < nChunk; c += gridDim.x) {
        long long base = (c << 11) + threadIdx.x;   // uint4 index
        uint4 v[8];
#pragma unroll
        for (int j = 0; j < 8; ++j) v[j] = xv[base + (j << 8)];

        uint32_t hit = 0;
        uint4 o[8];
#pragma unroll
        for (int j = 0; j < 8; ++j) {
            uint32_t u;
            u = v[j].x & MASK31;
            { uint32_t hb = (u >= uHi) ? 1u : 0u; myHi += hb; o[j].x = hb ? v[j].x : 0u;
              hit |= ((u - uLo) < span) ? (1u << (j * 4 + 0)) : 0u; }
            u = v[j].y & MASK31;
            { uint32_t hb = (u >= uHi) ? 1u : 0u; myHi += hb; o[j].y = hb ? v[j].y : 0u;
              hit |= ((u - uLo) < span) ? (1u << (j * 4 + 1)) : 0u; }
            u = v[j].z & MASK31;
            { uint32_t hb = (u >= uHi) ? 1u : 0u; myHi += hb; o[j].z = hb ? v[j].z : 0u;
              hit |= ((u - uLo) < span) ? (1u << (j * 4 + 2)) : 0u; }
            u = v[j].w & MASK31;
            { uint32_t hb = (u >= uHi) ? 1u : 0u; myHi += hb; o[j].w = hb ? v[j].w : 0u;
              hit |= ((u - uLo) < span) ? (1u << (j * 4 + 3)) : 0u; }
        }
#pragma unroll
        for (int j = 0; j < 8; ++j) ov[base + (j << 8)] = o[j];

        if (hit) {
            uint32_t e0 = (uint32_t)(base << 2);
#pragma unroll
            for (int j = 0; j < 8; ++j) {
                if (hit & (1u << (j * 4 + 0))) PUSH_PAIR(v[j].x, e0 + (uint32_t)(j << 10) + 0u)
                if (hit & (1u << (j * 4 + 1))) PUSH_PAIR(v[j].y, e0 + (uint32_t)(j << 10) + 1u)
                if (hit & (1u << (j * 4 + 2))) PUSH_PAIR(v[j].z, e0 + (uint32_t)(j << 10) + 2u)
                if (hit & (1u << (j * 4 + 3))) PUSH_PAIR(v[j].w, e0 + (uint32_t)(j << 10) + 3u)
            }
        }
    }

    // generic tail (elements beyond full chunks); empty for n = 2^25
    long long tailStart = nChunk << 13;    // chunks * 2048 uint4 * 4 elem
    if (blockIdx.x == 0) {
        for (long long idx = tailStart + threadIdx.x; idx < n; idx += NTHR) {
            uint32_t v = x[idx];
            uint32_t u = v & MASK31;
            uint32_t hb = (u >= uHi) ? 1u : 0u; myHi += hb;
            if ((u - uLo) < span) PUSH_PAIR(v, (uint32_t)idx)
            out[idx] = hb ? v : 0u;
        }
    }

    if (myHi) atomicAdd(&sHi, myHi);
    __syncthreads();
    if (threadIdx.x == 0) {
        uint32_t c2 = cnt < STG_CAP ? cnt : STG_CAP;
        cnt = c2;
        sBase = atomicAdd(&ws[SCL_OFF + 5], c2);
        if (sHi) atomicAdd(&ws[SCL_OFF + 4], sHi);
    }
    __syncthreads();
    uint32_t c2 = cnt, b0 = sBase;
    for (uint32_t q = threadIdx.x; q < c2; q += NTHR)
        if (b0 + q < PAIRS_CAP) gpairs[b0 + q] = stage[q];
#undef PUSH_PAIR
}

// ---- candidate histogram ----------------------------------------------------
__global__ void cand_hist_kernel(uint32_t* __restrict__ ws) {
    __shared__ uint32_t lh[CH_BINS];
    uint32_t G = ws[SCL_OFF + 5]; if (G > PAIRS_CAP) G = PAIRS_CAP;
    uint32_t spanBase = ws[SCL_OFF + 3], shift1 = ws[SCL_OFF + 2];
    for (int i = threadIdx.x; i < CH_BINS; i += NTHR) lh[i] = 0;
    __syncthreads();
    const uint2* pairs = (const uint2*)(ws + PAIRS_OFF);
    uint32_t stride = gridDim.x * NTHR;
    for (uint32_t i = blockIdx.x * NTHR + threadIdx.x; i < G; i += stride) {
        uint32_t u = pairs[i].x & MASK31;
        atomicAdd(&lh[((u - spanBase) >> shift1) & (CH_BINS - 1)], 1u);
    }
    __syncthreads();
    for (int i = threadIdx.x; i < CH_BINS; i += NTHR)
        if (lh[i]) atomicAdd(&ws[CH_OFF + i], lh[i]);
}

// ---- level-2 select (redundant per block) + gather in-bin pairs -------------
__global__ void sel_gather_kernel(uint32_t* __restrict__ ws, uint32_t k) {
    __shared__ uint32_t lh[CH_BINS];
    __shared__ uint32_t csum[NTHR];
    __shared__ uint32_t cpre[NTHR];
    __shared__ uint32_t sBase2, sRem2;
    for (int i = threadIdx.x; i < CH_BINS; i += NTHR) lh[i] = ws[CH_OFF + i];
    __syncthreads();
    uint32_t kp = k - ws[SCL_OFF + 4];
    uint32_t s = 0;
    for (int i = 0; i < 16; ++i) s += lh[threadIdx.x * 16 + i];
    csum[threadIdx.x] = s;
    __syncthreads();
    if (threadIdx.x == 0) {
        uint32_t run = 0;
        for (int c = NTHR - 1; c >= 0; --c) { cpre[c] = run; run += csum[c]; }
    }
    __syncthreads();
    if (cpre[threadIdx.x] < kp && kp <= cpre[threadIdx.x] + csum[threadIdx.x]) {
        uint32_t excl = cpre[threadIdx.x];
        for (int bb = threadIdx.x * 16 + 15; bb >= threadIdx.x * 16; --bb) {
            uint32_t cnt = lh[bb];
            if (excl + cnt >= kp) {
                sBase2 = ws[SCL_OFF + 3] + (((uint32_t)bb) << ws[SCL_OFF + 2]);
                sRem2 = kp - excl;
                break;
            }
            excl += cnt;
        }
    }
    __syncthreads();
    if (threadIdx.x == 0) { ws[SCL_OFF + 6] = sBase2; ws[SCL_OFF + 7] = sRem2; }
    uint32_t base2 = sBase2;
    uint32_t width = 1u << ws[SCL_OFF + 2];
    uint32_t G = ws[SCL_OFF + 5]; if (G > PAIRS_CAP) G = PAIRS_CAP;
    const uint2* pairs = (const uint2*)(ws + PAIRS_OFF);
    uint2* l3 = (uint2*)(ws + L3_OFF);
    uint32_t stride = gridDim.x * NTHR;
    for (uint32_t i = blockIdx.x * NTHR + threadIdx.x; i < G; i += stride) {
        uint2 pr = pairs[i];
        uint32_t u = pr.x & MASK31;
        if (u - base2 < width) {
            uint32_t p = atomicAdd(&ws[SCL_OFF + 8], 1u);
            if (p < L3_CAP) l3[p] = pr;
        }
    }
}

// ---- final select (redundant per block) + scatter-fixup kept candidates ----
__global__ void final_fixup_kernel(uint32_t* __restrict__ ws,
                                   uint32_t* __restrict__ out) {
    __shared__ uint32_t lh[CH_BINS];
    __shared__ uint32_t csum[NTHR];
    __shared__ uint32_t cpre[NTHR];
    __shared__ uint32_t tieIdx[TIE_CAP];
    __shared__ uint32_t tieCnt, sT, sJ, sTieMax;
    uint32_t c3 = ws[SCL_OFF + 8]; if (c3 > L3_CAP) c3 = L3_CAP;
    uint32_t base2 = ws[SCL_OFF + 6], rem2 = ws[SCL_OFF + 7];
    for (int i = threadIdx.x; i < CH_BINS; i += NTHR) lh[i] = 0;
    if (threadIdx.x == 0) tieCnt = 0;
    __syncthreads();
    const uint2* l3 = (const uint2*)(ws + L3_OFF);
    for (uint32_t i = threadIdx.x; i < c3; i += NTHR) {
        uint32_t u = l3[i].x & MASK31;
        atomicAdd(&lh[(u - base2) & (CH_BINS - 1)], 1u);
    }
    __syncthreads();
    uint32_t s = 0;
    for (int i = 0; i < 16; ++i) s += lh[threadIdx.x * 16 + i];
    csum[threadIdx.x] = s;
    __syncthreads();
    if (threadIdx.x == 0) {
        uint32_t run = 0;
        for (int c = NTHR - 1; c >= 0; --c) { cpre[c] = run; run += csum[c]; }
    }
    __syncthreads();
    if (cpre[threadIdx.x] < rem2 && rem2 <= cpre[threadIdx.x] + csum[threadIdx.x]) {
        uint32_t excl = cpre[threadIdx.x];
        for (int bb = threadIdx.x * 16 + 15; bb >= threadIdx.x * 16; --bb) {
            uint32_t cnt = lh[bb];
            if (excl + cnt >= rem2) { sT = base2 + (uint32_t)bb; sJ = rem2 - excl; break; }
            excl += cnt;
        }
    }
    __syncthreads();
    uint32_t t = sT;
    for (uint32_t i = threadIdx.x; i < c3; i += NTHR) {
        uint2 pr = l3[i];
        if ((pr.x & MASK31) == t) {
            uint32_t p = atomicAdd(&tieCnt, 1u);
            if (p < TIE_CAP) tieIdx[p] = pr.y;
        }
    }
    __syncthreads();
    if (threadIdx.x == 0) {
        uint32_t m = tieCnt < TIE_CAP ? tieCnt : TIE_CAP;
        for (uint32_t a = 1; a < m; ++a) {   // tiny insertion sort
            uint32_t v = tieIdx[a]; int bp = (int)a - 1;
            while (bp >= 0 && tieIdx[bp] > v) { tieIdx[bp + 1] = tieIdx[bp]; --bp; }
            tieIdx[bp + 1] = v;
        }
        uint32_t j = sJ;
        if (j > m) j = m;
        sJ = j;
        sTieMax = (j > 0) ? tieIdx[j - 1] : 0u;
    }
    __syncthreads();
    uint32_t j = sJ, tieMax = sTieMax;
    uint32_t G = ws[SCL_OFF + 5]; if (G > PAIRS_CAP) G = PAIRS_CAP;
    const uint2* pairs = (const uint2*)(ws + PAIRS_OFF);
    uint32_t stride = gridDim.x * NTHR;
    for (uint32_t i = blockIdx.x * NTHR + threadIdx.x; i < G; i += stride) {
        uint2 pr = pairs[i];
        uint32_t u = pr.x & MASK31;
        bool keep = (u > t) || (u == t && j > 0 && pr.y <= tieMax);
        if (keep) out[pr.y] = pr.x;
    }
}

extern "C" void kernel_launch(void* const* d_in, const int* in_sizes, int n_in,
                              void* d_out, int out_size, void* d_ws, size_t ws_size,
                              hipStream_t stream) {
    const uint32_t* x = (const uint32_t*)d_in[0];
    uint32_t* out = (uint32_t*)d_out;
    uint32_t* ws = (uint32_t*)d_ws;
    long long n = (long long)in_sizes[0];

    const double ratio = 0.5;  // SPARSE_COMPRESSION_RATIO
    long long k = (long long)((double)n * (1.0 - ratio));
    if (k < 1) k = 1;
    if (k > n) k = n;

    long long n4 = n >> 2;
    long long S = (n4 >> 5) << 2;           // 4 samples per 32 uint4s
    long long ks = (long long)((double)k * ((double)S / (double)n));
    const long long M = 4500;               // ~8.8 sigma at S=1,048,576
    uint32_t ksmM = (uint32_t)((ks - M) < 1 ? 1 : (ks - M));
    uint32_t kspM = (uint32_t)((ks + M) > S ? S : (ks + M));

    zero_ws_kernel<<<(ZERO_WORDS + NTHR - 1) / NTHR, NTHR, 0, stream>>>(ws);
    sample_hist_kernel<<<256, NTHR, 0, stream>>>((const uint4*)x, n4, ws);
    sel_bracket_kernel<<<1, NTHR, 0, stream>>>(ws, ksmM, kspM);
    fused_main_kernel<<<2048, NTHR, 0, stream>>>(x, out, n, ws);
    cand_hist_kernel<<<256, NTHR, 0, stream>>>(ws);
    sel_gather_kernel<<<256, NTHR, 0, stream>>>(ws, (uint32_t)k);
    final_fixup_kernel<<<256, NTHR, 0, stream>>>(ws, out);
}